// Round 8
// baseline (205.917 us; speedup 1.0000x reference)
//
#include <hip/hip_runtime.h>

// Fixed-shape problem
#define NBATCH 4
#define NPTS   8192
#define MTGT   8192
#define BN     (NBATCH*NPTS)      // 32768 sources
#define TPB    256
#define SPT    16                 // sources per thread (ALL in named scalars)
#define SPB    (TPB*SPT)          // 4096 sources per block
#define NXBLK  (BN/SPB)           // 8
#define CHUNK  64                 // targets staged per block
#define NCHUNK (MTGT/CHUNK)       // 128 -> grid 8x128 = 1024 blocks (4/CU)

// Monotone float->uint key: preserves float ordering under unsigned compare.
// atomicMin lattice -> bit-deterministic end state for any schedule
// (passed post-timing validation in rounds 1/2/5/6/7).
__device__ __forceinline__ unsigned f2key(float x) {
    unsigned u = __float_as_uint(x);
    return (u & 0x80000000u) ? ~u : (u | 0x80000000u);
}
__device__ __forceinline__ float key2f(unsigned k) {
    return __uint_as_float((k & 0x80000000u) ? (k ^ 0x80000000u) : ~k);
}

__global__ __launch_bounds__(256) void init_kernel(unsigned* __restrict__ wsmin) {
    int i = blockIdx.x * 256 + threadIdx.x;
    wsmin[i] = 0xFFFFFFFFu;   // +inf in key space
}

// --- macro machinery: 16 sources as named scalars (NO arrays -> NO scratch) ---
#define FOR16(X) X(0) X(1) X(2) X(3) X(4) X(5) X(6) X(7) \
                 X(8) X(9) X(10) X(11) X(12) X(13) X(14) X(15)

#define DECL_S(i) float ax##i, ay##i, az##i, bm##i = 3e38f;

// group g occupies float4 sv[3g..3g+2]; sources A..D = 4g..4g+3
#define LOAD_G(g, A, B, C, D)                                         \
    {   float4 qa = sv[3*(g)], qb = sv[3*(g)+1], qc = sv[3*(g)+2];    \
        ax##A = -2.f*qa.x; ay##A = -2.f*qa.y; az##A = -2.f*qa.z;      \
        ax##B = -2.f*qa.w; ay##B = -2.f*qb.x; az##B = -2.f*qb.y;      \
        ax##C = -2.f*qb.z; ay##C = -2.f*qb.w; az##C = -2.f*qc.x;      \
        ax##D = -2.f*qc.y; ay##D = -2.f*qc.z; az##D = -2.f*qc.w; }

#define BODY(i)                                                                   \
    {   float d0 = fmaf(ax##i, t0.x, fmaf(ay##i, t0.y, fmaf(az##i, t0.z, t0.w))); \
        float d1 = fmaf(ax##i, t1.x, fmaf(ay##i, t1.y, fmaf(az##i, t1.z, t1.w))); \
        bm##i = fminf(bm##i, fminf(d0, d1)); }

#define EMIT(i)                                                       \
    {   unsigned k = f2key(bm##i);                                    \
        if (k < wsmin[s0 + (i)]) atomicMin(&wsmin[s0 + (i)], k); }

// Per source point, min over one 64-target chunk of d' = ||t||^2 - 2 s.t
// (exact sq distance = d' + ||s||^2, added in reduce)
__global__ __launch_bounds__(TPB) void nn_min_kernel(const float* __restrict__ src,
                                                     const float* __restrict__ tgt,
                                                     unsigned* __restrict__ wsmin) {
    __shared__ float  raw[CHUNK * 3];   // 768 B
    __shared__ float4 lt[CHUNK];        // 1 KiB: (x,y,z,||t||^2); invalid -> 1e30

    const int tid = threadIdx.x;
    const int bx  = blockIdx.x;            // 0..7   (source slice)
    const int c   = blockIdx.y;            // 0..127 (target chunk)
    const int b   = bx >> 1;               // 2 x-blocks per batch

    // ---- stage CHUNK targets (768 B) ----
    const float4* tv = reinterpret_cast<const float4*>(
        tgt + ((size_t)b * MTGT + (size_t)c * CHUNK) * 3);
    if (tid < CHUNK * 3 / 4) reinterpret_cast<float4*>(raw)[tid] = tv[tid];
    __syncthreads();
    if (tid < CHUNK) {
        float x = raw[3 * tid], y = raw[3 * tid + 1], z = raw[3 * tid + 2];
        float tsq = fmaf(x, x, fmaf(y, y, z * z));
        bool valid = (x != 0.f) || (y != 0.f) || (z != 0.f);
        lt[tid] = make_float4(x, y, z, valid ? tsq : 1e30f);
    }
    __syncthreads();

    // ---- 16 source points: 12 contiguous float4 = 192 B per thread ----
    const int s0 = bx * SPB + tid * SPT;
    const float4* sv = reinterpret_cast<const float4*>(src + (size_t)s0 * 3);

    FOR16(DECL_S)
    LOAD_G(0,  0,  1,  2,  3)
    LOAD_G(1,  4,  5,  6,  7)
    LOAD_G(2,  8,  9, 10, 11)
    LOAD_G(3, 12, 13, 14, 15)

    // ---- inner loop: 2 broadcast ds_read_b128 feed 112 VALU instructions ----
#pragma unroll 2
    for (int m = 0; m < CHUNK; m += 2) {
        float4 t0 = lt[m], t1 = lt[m + 1];
        FOR16(BODY)
    }

    // ---- combine: cached pre-check + atomicMin (stale >= current -> safe skip) ----
    FOR16(EMIT)
}

// 32 blocks: (batch, slice-of-1024-sources). Deterministic double partials.
__global__ __launch_bounds__(256) void reduce_kernel(const float* __restrict__ src,
                                                     const unsigned* __restrict__ wsmin,
                                                     double* __restrict__ partials) {
    const int blk = blockIdx.x;          // 0..31
    const int b = blk >> 3, slice = blk & 7;
    const int tid = threadIdx.x;

    double sum = 0.0, cnt = 0.0;
#pragma unroll
    for (int k = 0; k < 4; ++k) {
        int gid = b * NPTS + slice * 1024 + k * 256 + tid;
        float sx = src[(size_t)gid * 3 + 0];
        float sy = src[(size_t)gid * 3 + 1];
        float sz = src[(size_t)gid * 3 + 2];
        bool valid = (sx != 0.f) || (sy != 0.f) || (sz != 0.f);
        float ssq = fmaf(sx, sx, fmaf(sy, sy, sz * sz));
        float sq = fmaxf(0.f, ssq + key2f(wsmin[gid]));
        if (valid) { sum += (double)sq; cnt += 1.0; }
    }

    __shared__ double sh[512];
    sh[tid] = sum; sh[256 + tid] = cnt;
    __syncthreads();
    for (int s = 128; s > 0; s >>= 1) {
        if (tid < s) { sh[tid] += sh[tid + s]; sh[256 + tid] += sh[256 + tid + s]; }
        __syncthreads();
    }
    if (tid == 0) { partials[2 * blk] = sh[0]; partials[2 * blk + 1] = sh[256]; }
}

// Fixed-order final combine: bit-deterministic scalar output.
__global__ void final_kernel(const double* __restrict__ partials, float* __restrict__ out) {
    __shared__ double bmv[4];
    int t = threadIdx.x;
    if (t < 4) {
        double s = 0.0, c = 0.0;
        for (int i = 0; i < 8; ++i) {
            s += partials[2 * (t * 8 + i)];
            c += partials[2 * (t * 8 + i) + 1];
        }
        if (c < 1.0) c = 1.0;
        bmv[t] = s / (3.0 * c);
    }
    __syncthreads();
    if (t == 0) out[0] = (float)((bmv[0] + bmv[1] + bmv[2] + bmv[3]) * 0.25);
}

extern "C" void kernel_launch(void* const* d_in, const int* in_sizes, int n_in,
                              void* d_out, int out_size, void* d_ws, size_t ws_size,
                              hipStream_t stream) {
    const float* src = (const float*)d_in[0];
    const float* tgt = (const float*)d_in[1];
    float* out = (float*)d_out;

    unsigned* wsmin  = (unsigned*)d_ws;                                        // 128 KiB
    double* partials = (double*)((char*)d_ws + (size_t)BN * sizeof(unsigned)); // 512 B

    init_kernel<<<dim3(BN / 256), dim3(256), 0, stream>>>(wsmin);
    nn_min_kernel<<<dim3(NXBLK, NCHUNK), dim3(TPB), 0, stream>>>(src, tgt, wsmin);
    reduce_kernel<<<dim3(32), dim3(256), 0, stream>>>(src, wsmin, partials);
    final_kernel<<<dim3(1), dim3(64), 0, stream>>>(partials, out);
}

// Round 9
// 41.468 us; speedup vs baseline: 4.9657x; 4.9657x over previous
//
#include <hip/hip_runtime.h>

// Fixed-shape problem
#define NBATCH 4
#define NPTS   8192
#define MTGT   8192
#define BN     (NBATCH*NPTS)      // 32768 sources
#define TPB    256
#define SPT    4                  // sources per thread (static-indexed arrays)
#define SPB    (TPB*SPT)          // 1024 sources per block (slice)
#define NXBLK  (BN/SPB)           // 32 slices (8 per batch)
#define CHUNK  256                // targets staged per block
#define NCHUNK (MTGT/CHUNK)       // 32 -> grid 32x32 = 1024 blocks (4/CU)

// wspart layout: [slice][chunk][source-in-slice] -> both writer and reader
// are fully coalesced; 4 MB of plain streaming stores, no atomics anywhere.

// Per source point, min over one 256-target chunk of d' = ||t||^2 - 2 s.t
// (exact sq distance = d' + ||s||^2, added in reduce)
__global__ __launch_bounds__(TPB) void nn_min_kernel(const float* __restrict__ src,
                                                     const float* __restrict__ tgt,
                                                     float* __restrict__ wspart) {
    __shared__ float  raw[CHUNK * 3];   // 3 KiB
    __shared__ float4 lt[CHUNK];        // 4 KiB: (x,y,z,||t||^2); invalid -> 1e30

    const int tid = threadIdx.x;
    const int bx  = blockIdx.x;          // 0..31 (source slice)
    const int c   = blockIdx.y;          // 0..31 (target chunk)
    const int b   = bx >> 3;             // 8 slices per batch

    // ---- stage CHUNK targets (3 KiB, coalesced float4) ----
    const float4* tv = reinterpret_cast<const float4*>(
        tgt + ((size_t)b * MTGT + (size_t)c * CHUNK) * 3);
    if (tid < CHUNK * 3 / 4) reinterpret_cast<float4*>(raw)[tid] = tv[tid];
    __syncthreads();
    {
        float x = raw[3 * tid], y = raw[3 * tid + 1], z = raw[3 * tid + 2];
        float tsq = fmaf(x, x, fmaf(y, y, z * z));
        bool valid = (x != 0.f) || (y != 0.f) || (z != 0.f);
        lt[tid] = make_float4(x, y, z, valid ? tsq : 1e30f);
    }
    __syncthreads();

    // ---- 4 source points: 3 contiguous float4 = 48 B per thread ----
    const int s0 = bx * SPB + tid * SPT;
    const float4* sv = reinterpret_cast<const float4*>(src + (size_t)s0 * 3);
    float4 q0 = sv[0], q1 = sv[1], q2 = sv[2];
    float sxs[4] = {q0.x, q0.w, q1.z, q2.y};
    float sys[4] = {q0.y, q1.x, q1.w, q2.z};
    float szs[4] = {q0.z, q1.y, q2.x, q2.w};

    float ax[4], ay[4], az[4], bm[4];
#pragma unroll
    for (int j = 0; j < 4; ++j) {
        ax[j] = -2.f * sxs[j];
        ay[j] = -2.f * sys[j];
        az[j] = -2.f * szs[j];
        bm[j] = 3e38f;
    }

    // ---- inner loop (R2-proven shape): direct lt[m], 2 targets/iter,
    //      fminf(bm, fminf(d0,d1)) fusable to v_min3_f32 ----
#pragma unroll 2
    for (int m = 0; m < CHUNK; m += 2) {
        float4 t0 = lt[m], t1 = lt[m + 1];
#pragma unroll
        for (int j = 0; j < 4; ++j) {
            float d0 = fmaf(ax[j], t0.x, fmaf(ay[j], t0.y, fmaf(az[j], t0.z, t0.w)));
            float d1 = fmaf(ax[j], t1.x, fmaf(ay[j], t1.y, fmaf(az[j], t1.z, t1.w)));
            bm[j] = fminf(bm[j], fminf(d0, d1));
        }
    }

    // ---- one coalesced 16B store per thread ----
    reinterpret_cast<float4*>(wspart + ((size_t)bx * NCHUNK + c) * SPB)[tid] =
        make_float4(bm[0], bm[1], bm[2], bm[3]);
}

// 32 blocks, one per slice: min over 32 chunk-partials (coalesced reads:
// for fixed (k,c) a wave reads 256 consecutive bytes), then weighted sums.
__global__ __launch_bounds__(256) void reduce_kernel(const float* __restrict__ src,
                                                     const float* __restrict__ wspart,
                                                     double* __restrict__ partials) {
    const int bx  = blockIdx.x;          // slice 0..31
    const int tid = threadIdx.x;
    const float* wp = wspart + (size_t)bx * NCHUNK * SPB;

    double sum = 0.0, cnt = 0.0;
#pragma unroll
    for (int k = 0; k < 4; ++k) {
        const int s = k * 256 + tid;     // source within slice
        const int gid = bx * SPB + s;

        float m = 3e38f;
#pragma unroll 4
        for (int c = 0; c < NCHUNK; ++c) m = fminf(m, wp[c * SPB + s]);

        float sx = src[(size_t)gid * 3 + 0];
        float sy = src[(size_t)gid * 3 + 1];
        float sz = src[(size_t)gid * 3 + 2];
        bool valid = (sx != 0.f) || (sy != 0.f) || (sz != 0.f);
        float ssq = fmaf(sx, sx, fmaf(sy, sy, sz * sz));
        float sq = fmaxf(0.f, ssq + m);
        if (valid) { sum += (double)sq; cnt += 1.0; }
    }

    __shared__ double sh[512];
    sh[tid] = sum; sh[256 + tid] = cnt;
    __syncthreads();
    for (int s = 128; s > 0; s >>= 1) {
        if (tid < s) { sh[tid] += sh[tid + s]; sh[256 + tid] += sh[256 + tid + s]; }
        __syncthreads();
    }
    if (tid == 0) { partials[2 * bx] = sh[0]; partials[2 * bx + 1] = sh[256]; }
}

// Fixed-order final combine: bit-deterministic scalar output.
// Slices 0..7 -> batch 0, 8..15 -> batch 1, etc.
__global__ void final_kernel(const double* __restrict__ partials, float* __restrict__ out) {
    __shared__ double bmv[4];
    int t = threadIdx.x;
    if (t < 4) {
        double s = 0.0, c = 0.0;
        for (int i = 0; i < 8; ++i) {
            s += partials[2 * (t * 8 + i)];
            c += partials[2 * (t * 8 + i) + 1];
        }
        if (c < 1.0) c = 1.0;
        bmv[t] = s / (3.0 * c);
    }
    __syncthreads();
    if (t == 0) out[0] = (float)((bmv[0] + bmv[1] + bmv[2] + bmv[3]) * 0.25);
}

extern "C" void kernel_launch(void* const* d_in, const int* in_sizes, int n_in,
                              void* d_out, int out_size, void* d_ws, size_t ws_size,
                              hipStream_t stream) {
    const float* src = (const float*)d_in[0];
    const float* tgt = (const float*)d_in[1];
    float* out = (float*)d_out;

    float*  wspart   = (float*)d_ws;                                  // 4 MiB
    double* partials = (double*)((char*)d_ws +
                                 (size_t)NXBLK * NCHUNK * SPB * sizeof(float)); // 512 B

    nn_min_kernel<<<dim3(NXBLK, NCHUNK), dim3(TPB), 0, stream>>>(src, tgt, wspart);
    reduce_kernel<<<dim3(NXBLK), dim3(256), 0, stream>>>(src, wspart, partials);
    final_kernel<<<dim3(1), dim3(64), 0, stream>>>(partials, out);
}